// Round 1
// baseline (1110.294 us; speedup 1.0000x reference)
//
#include <hip/hip_runtime.h>
#include <stdint.h>

#define N_U 20000
#define N_V 20000
#define N_E 320000
#define EPS_F 1e-5f
#define NEG_HUGE -3.402823466e38f

using bf16x8 = __attribute__((__ext_vector_type__(8))) __bf16;
using f32x4  = __attribute__((__ext_vector_type__(4))) float;

__device__ __forceinline__ unsigned short f2bf(float f) {
  unsigned int u = __float_as_uint(f);
  u += 0x7FFFu + ((u >> 16) & 1u);   // round-to-nearest-even
  return (unsigned short)(u >> 16);
}

// ---- attention logits: one wave per node, dot(x[i,:256], attn) ----
__global__ void k_logits(const float* __restrict__ x, const float* __restrict__ attn,
                         float* __restrict__ out, int n) {
  int wave = (blockIdx.x * blockDim.x + threadIdx.x) >> 6;
  int lane = threadIdx.x & 63;
  if (wave >= n) return;
  const float* xr = x + (size_t)wave * 256;
  float s = 0.f;
#pragma unroll
  for (int j = 0; j < 4; j++) s += xr[lane + j * 64] * attn[lane + j * 64];
#pragma unroll
  for (int o = 32; o; o >>= 1) s += __shfl_down(s, o);
  if (lane == 0) out[wave] = s;
}

// ---- global softmax stats (max, sumexp) — single block ----
__global__ void k_softmax_stat(const float* __restrict__ l, float* __restrict__ stat, int n) {
  __shared__ float red[16];
  __shared__ float sm;
  int t = threadIdx.x;
  float m = NEG_HUGE;
  for (int i = t; i < n; i += 1024) m = fmaxf(m, l[i]);
#pragma unroll
  for (int o = 32; o; o >>= 1) m = fmaxf(m, __shfl_down(m, o));
  if ((t & 63) == 0) red[t >> 6] = m;
  __syncthreads();
  if (t == 0) {
    float mm = red[0];
    for (int i = 1; i < 16; i++) mm = fmaxf(mm, red[i]);
    sm = mm;
  }
  __syncthreads();
  float mx = sm;
  float s = 0.f;
  for (int i = t; i < n; i += 1024) s += __expf(l[i] - mx);
#pragma unroll
  for (int o = 32; o; o >>= 1) s += __shfl_down(s, o);
  __syncthreads();
  if ((t & 63) == 0) red[t >> 6] = s;
  __syncthreads();
  if (t == 0) {
    float ss = 0.f;
    for (int i = 0; i < 16; i++) ss += red[i];
    stat[0] = mx;
    stat[1] = ss;
  }
}

__global__ void k_aw(const float* __restrict__ l, const float* __restrict__ stat,
                     float* __restrict__ aw, int n) {
  int i = blockIdx.x * 256 + threadIdx.x;
  if (i >= n) return;
  aw[i] = __expf(l[i] - stat[0]) * (1.f / stat[1]);
}

// ---- CSR build ----
__global__ void k_hist(const int* __restrict__ dst, int* __restrict__ cnt) {
  int e = blockIdx.x * 256 + threadIdx.x;
  atomicAdd(&cnt[dst[e]], 1);
}

__global__ void k_scan(const int* __restrict__ cnt, int* __restrict__ off,
                       int* __restrict__ cur, int n) {
  __shared__ int warpsum[16];
  __shared__ int carry;
  int t = threadIdx.x;
  if (t == 0) carry = 0;
  __syncthreads();
  for (int base = 0; base < n; base += 1024) {
    int i = base + t;
    int v = (i < n) ? cnt[i] : 0;
    int lane = t & 63, w = t >> 6;
    int incl = v;
#pragma unroll
    for (int o = 1; o < 64; o <<= 1) {
      int u = __shfl_up(incl, o);
      if (lane >= o) incl += u;
    }
    if (lane == 63) warpsum[w] = incl;
    __syncthreads();
    if (t == 0) {
      int s = 0;
      for (int k = 0; k < 16; k++) { int x = warpsum[k]; warpsum[k] = s; s += x; }
    }
    __syncthreads();
    int excl = incl - v + warpsum[w] + carry;
    if (i < n) { off[i] = excl; cur[i] = excl; }
    __syncthreads();
    if (t == 1023) carry = excl + v;
    __syncthreads();
  }
  if (t == 0) off[n] = carry;
}

__global__ void k_scatter(const int* __restrict__ dst, const int* __restrict__ src,
                          int* __restrict__ cur, int2* __restrict__ perm) {
  int e = blockIdx.x * 256 + threadIdx.x;
  int d = dst[e];
  int p = atomicAdd(&cur[d], 1);
  perm[p] = make_int2(e, src[e]);
}

// ---- per-destination aggregation: mean/max of weighted src feats + edge feats,
//      writes full bf16 h row [self(256)|mean_src(256)|max_src(256)|mean_e(64)|max_e(64)] ----
__global__ void k_aggregate(const float* __restrict__ xsrc, const float* __restrict__ aw,
                            const float* __restrict__ xe, const int* __restrict__ off,
                            const int2* __restrict__ perm, const float* __restrict__ xt,
                            unsigned short* __restrict__ h, int nd) {
  int u = blockIdx.x;
  if (u >= nd) return;
  int t = threadIdx.x;
  int beg = off[u], end = off[u + 1];
  float s = 0.f, mx = NEG_HUGE;
  float se = 0.f, me = NEG_HUGE;
  for (int j = beg; j < end; j++) {
    int2 es = perm[j];
    float a = aw[es.y];
    float wv = a * xsrc[(size_t)es.y * 256 + t];
    s += wv;
    mx = fmaxf(mx, wv);
    if (t < 64) {
      float xev = xe[(size_t)es.x * 64 + t];
      se += xev;
      me = fmaxf(me, xev);
    }
  }
  int deg = end - beg;
  float inv = 1.f / (float)(deg > 0 ? deg : 1);
  unsigned short* hr = h + (size_t)u * 896;
  hr[t] = f2bf(xt[(size_t)u * 256 + t]);
  hr[256 + t] = f2bf(s * inv);
  hr[512 + t] = f2bf(deg > 0 ? mx : 0.f);
  if (t < 64) {
    hr[768 + t] = f2bf(se * inv);
    hr[832 + t] = f2bf(deg > 0 ? me : 0.f);
  }
}

// ---- weight transpose + bf16: Wt[n][k] = W[k][n] ----
__global__ void k_wt(const float* __restrict__ W, unsigned short* __restrict__ Wt,
                     int K, int N) {
  int i = blockIdx.x * 256 + threadIdx.x;
  if (i >= K * N) return;
  int k = i / N, n = i % N;
  Wt[(size_t)n * K + k] = f2bf(W[i]);
}

// ---- f32 -> bf16 bulk convert (n4 = n/4) ----
__global__ void k_cvt(const float* __restrict__ x, unsigned short* __restrict__ y, int n4) {
  int i = blockIdx.x * 256 + threadIdx.x;
  if (i >= n4) return;
  float4 v = reinterpret_cast<const float4*>(x)[i];
  reinterpret_cast<ushort4*>(y)[i] = make_ushort4(f2bf(v.x), f2bf(v.y), f2bf(v.z), f2bf(v.w));
}

// ---- bf16 MFMA GEMM: C[M,N] = A[M,K] * Wt[N,K]^T.  TM=128, TN in {128,64}, BK=32. ----
template <int TN>
__global__ __launch_bounds__(256) void k_gemm(const unsigned short* __restrict__ A, int lda,
                                              const unsigned short* __restrict__ B, int ldb,
                                              float* __restrict__ C, int ldc, int M, int K) {
  constexpr int WAVES_N = TN / 64;       // 2 or 1
  constexpr int WAVES_M = 4 / WAVES_N;   // 2 or 4
  constexpr int WTM = 128 / WAVES_M;     // 64 or 32
  constexpr int MT = WTM / 16;           // 4 or 2
  constexpr int NT = 4;

  __shared__ __align__(16) unsigned short As[128 * 32];
  __shared__ __align__(16) unsigned short Bs[TN * 32];

  const int t = threadIdx.x;
  const int m0 = blockIdx.x * 128;
  const int n0 = blockIdx.y * TN;
  const int lane = t & 63;
  const int w = t >> 6;
  const int wm = w % WAVES_M;
  const int wn = w / WAVES_M;

  f32x4 acc[MT][NT];
#pragma unroll
  for (int i = 0; i < MT; i++)
#pragma unroll
    for (int j = 0; j < NT; j++) acc[i][j] = (f32x4){0.f, 0.f, 0.f, 0.f};

  const int arow_l = wm * WTM + (lane & 15);
  const int koff_l = (lane >> 4) * 8;

  for (int k0 = 0; k0 < K; k0 += 32) {
    if (k0) __syncthreads();
    // stage A tile: 128 x 32 bf16
#pragma unroll
    for (int p = 0; p < 2; p++) {
      int c = t + p * 256;
      int row = c >> 2, kc = c & 3;
      int rg = m0 + row;
      rg = rg < M ? rg : M - 1;
      *reinterpret_cast<uint4*>(&As[row * 32 + kc * 8]) =
          *reinterpret_cast<const uint4*>(A + (size_t)rg * lda + k0 + kc * 8);
    }
    // stage B tile: TN x 32 bf16 (Wt is [N][K])
#pragma unroll
    for (int p = 0; p < TN / 64; p++) {
      int c = t + p * 256;
      int row = c >> 2, kc = c & 3;
      *reinterpret_cast<uint4*>(&Bs[row * 32 + kc * 8]) =
          *reinterpret_cast<const uint4*>(B + (size_t)(n0 + row) * ldb + k0 + kc * 8);
    }
    __syncthreads();
    bf16x8 af[MT], bfv[NT];
#pragma unroll
    for (int i = 0; i < MT; i++)
      af[i] = *reinterpret_cast<const bf16x8*>(&As[(arow_l + i * 16) * 32 + koff_l]);
#pragma unroll
    for (int j = 0; j < NT; j++)
      bfv[j] = *reinterpret_cast<const bf16x8*>(&Bs[(wn * 64 + j * 16 + (lane & 15)) * 32 + koff_l]);
#pragma unroll
    for (int i = 0; i < MT; i++)
#pragma unroll
      for (int j = 0; j < NT; j++)
        acc[i][j] = __builtin_amdgcn_mfma_f32_16x16x32_bf16(af[i], bfv[j], acc[i][j], 0, 0, 0);
  }
  // epilogue: D lane map col=lane&15, row=(lane>>4)*4+r
#pragma unroll
  for (int i = 0; i < MT; i++) {
#pragma unroll
    for (int j = 0; j < NT; j++) {
      int col = n0 + wn * 64 + j * 16 + (lane & 15);
#pragma unroll
      for (int r = 0; r < 4; r++) {
        int row = m0 + wm * WTM + i * 16 + (lane >> 4) * 4 + r;
        if (row < M) C[(size_t)row * ldc + col] = acc[i][j][r];
      }
    }
  }
}

// ---- edge assemble: out_e += pu[row] + pv[col], accumulate BN col stats ----
__global__ void k_edge_assemble(float* __restrict__ OutE, const float* __restrict__ pu,
                                const float* __restrict__ pv, const int* __restrict__ rowe,
                                const int* __restrict__ cole, float* __restrict__ sum,
                                float* __restrict__ sumsq) {
  __shared__ float sred[4][64];
  __shared__ float qred[4][64];
  int t = threadIdx.x;
  int c = t & 63, g = t >> 6;
  long e0 = (long)blockIdx.x * 64 + g * 16;
  float s = 0.f, q = 0.f;
  for (int j = 0; j < 16; j++) {
    long e = e0 + j;
    int ru = rowe[e], cv = cole[e];
    float val = OutE[e * 64 + c] + pu[(size_t)ru * 64 + c] + pv[(size_t)cv * 64 + c];
    OutE[e * 64 + c] = val;
    s += val;
    q += val * val;
  }
  sred[g][c] = s;
  qred[g][c] = q;
  __syncthreads();
  if (g == 0) {
    s = sred[0][c] + sred[1][c] + sred[2][c] + sred[3][c];
    q = qred[0][c] + qred[1][c] + qred[2][c] + qred[3][c];
    atomicAdd(&sum[c], s);
    atomicAdd(&sumsq[c], q);
  }
}

// ---- column stats for 256-col matrices ----
__global__ void k_colstats256(const float* __restrict__ X, int nrows, float* __restrict__ sum,
                              float* __restrict__ sumsq) {
  int c = threadIdx.x;
  int rows_per = (nrows + gridDim.x - 1) / gridDim.x;
  int r0 = blockIdx.x * rows_per;
  int r1 = min(nrows, r0 + rows_per);
  float s = 0.f, q = 0.f;
  for (int r = r0; r < r1; r++) {
    float v = X[(size_t)r * 256 + c];
    s += v;
    q += v * v;
  }
  atomicAdd(&sum[c], s);
  atomicAdd(&sumsq[c], q);
}

// ---- BN apply in place ----
__global__ void k_bn(float* __restrict__ X, long n, int cmask, const float* __restrict__ sum,
                     const float* __restrict__ sumsq, const float* __restrict__ g,
                     const float* __restrict__ be, float invn) {
  long i = (long)blockIdx.x * 256 + threadIdx.x;
  if (i >= n) return;
  int c = (int)(i & cmask);
  float mu = sum[c] * invn;
  float var = sumsq[c] * invn - mu * mu;
  float x = X[i];
  X[i] = (x - mu) * rsqrtf(var + EPS_F) * g[c] + be[c];
}

extern "C" void kernel_launch(void* const* d_in, const int* in_sizes, int n_in, void* d_out,
                              int out_size, void* d_ws, size_t ws_size, hipStream_t stream) {
  (void)in_sizes; (void)n_in; (void)out_size; (void)ws_size;
  const float* xus = (const float*)d_in[0];
  const float* xut = (const float*)d_in[1];
  const float* xvs = (const float*)d_in[2];
  const float* xvt = (const float*)d_in[3];
  const float* xe_e = (const float*)d_in[4];
  const float* xe_v2u = (const float*)d_in[5];
  const float* xe_u2v = (const float*)d_in[6];
  const int* row_v2u = (const int*)d_in[7];
  const int* col_v2u = (const int*)d_in[8];
  const int* row_u2v = (const int*)d_in[9];
  const int* col_u2v = (const int*)d_in[10];
  const int* row_e = (const int*)d_in[11];
  const int* col_e = (const int*)d_in[12];
  const float* attn_v2u = (const float*)d_in[13];
  const float* W_v2u = (const float*)d_in[14];
  const float* g_v2u = (const float*)d_in[16];
  const float* be_v2u = (const float*)d_in[17];
  const float* attn_u2v = (const float*)d_in[18];
  const float* W_u2v = (const float*)d_in[19];
  const float* g_u2v = (const float*)d_in[21];
  const float* be_u2v = (const float*)d_in[22];
  const float* W_e = (const float*)d_in[23];
  const float* g_e = (const float*)d_in[25];
  const float* be_e = (const float*)d_in[26];

  char* p = (char*)d_ws;
  auto alloc = [&](size_t bytes) {
    char* r = p;
    p += (bytes + 15) & ~(size_t)15;
    return r;
  };
  // --- zero zone (contiguous prefix) ---
  int* cnt_u = (int*)alloc(N_U * 4);
  int* cnt_v = (int*)alloc(N_V * 4);
  float* stats = (float*)alloc(1152 * 4);
  size_t zero_bytes = (size_t)(p - (char*)d_ws);
  float* sum_u = stats, *sq_u = stats + 256;
  float* sum_v = stats + 512, *sq_v = stats + 768;
  float* sum_e = stats + 1024, *sq_e = stats + 1088;
  // --- rest ---
  int* off_u = (int*)alloc((N_U + 1) * 4);
  int* cur_u = (int*)alloc(N_U * 4);
  int2* perm_u = (int2*)alloc((size_t)N_E * 8);
  int* off_v = (int*)alloc((N_V + 1) * 4);
  int* cur_v = (int*)alloc(N_V * 4);
  int2* perm_v = (int2*)alloc((size_t)N_E * 8);
  float* logits_u = (float*)alloc(N_U * 4);
  float* logits_v = (float*)alloc(N_V * 4);
  float* aw_u = (float*)alloc(N_U * 4);
  float* aw_v = (float*)alloc(N_V * 4);
  float* smstat = (float*)alloc(8 * 4);
  unsigned short* h_u = (unsigned short*)alloc((size_t)N_U * 896 * 2);
  unsigned short* h_v = (unsigned short*)alloc((size_t)N_V * 896 * 2);
  unsigned short* xe_bf = (unsigned short*)alloc((size_t)N_E * 64 * 2);
  unsigned short* Wt_v2u = (unsigned short*)alloc((size_t)896 * 256 * 2);
  unsigned short* Wt_u2v = (unsigned short*)alloc((size_t)896 * 256 * 2);
  unsigned short* Wt_e = (unsigned short*)alloc((size_t)576 * 64 * 2);
  float* pu = (float*)alloc((size_t)N_U * 64 * 4);
  float* pv = (float*)alloc((size_t)N_V * 64 * 4);

  float* out_u = (float*)d_out;
  float* out_v = out_u + (size_t)N_U * 256;
  float* out_e = out_v + (size_t)N_V * 256;

  hipMemsetAsync(d_ws, 0, zero_bytes, stream);

  // softmax attention weights
  k_logits<<<5000, 256, 0, stream>>>(xus, attn_u2v, logits_u, N_U);
  k_logits<<<5000, 256, 0, stream>>>(xvs, attn_v2u, logits_v, N_V);
  k_softmax_stat<<<1, 1024, 0, stream>>>(logits_u, smstat, N_U);
  k_softmax_stat<<<1, 1024, 0, stream>>>(logits_v, smstat + 4, N_V);
  k_aw<<<79, 256, 0, stream>>>(logits_u, smstat, aw_u, N_U);
  k_aw<<<79, 256, 0, stream>>>(logits_v, smstat + 4, aw_v, N_V);

  // CSR build: v2u segments by row_v2u over U; u2v segments by col_u2v over V
  k_hist<<<1250, 256, 0, stream>>>(row_v2u, cnt_u);
  k_hist<<<1250, 256, 0, stream>>>(col_u2v, cnt_v);
  k_scan<<<1, 1024, 0, stream>>>(cnt_u, off_u, cur_u, N_U);
  k_scan<<<1, 1024, 0, stream>>>(cnt_v, off_v, cur_v, N_V);
  k_scatter<<<1250, 256, 0, stream>>>(row_v2u, col_v2u, cur_u, perm_u);
  k_scatter<<<1250, 256, 0, stream>>>(col_u2v, row_u2v, cur_v, perm_v);

  // aggregation -> bf16 h matrices
  k_aggregate<<<N_U, 256, 0, stream>>>(xvs, aw_v, xe_v2u, off_u, perm_u, xut, h_u, N_U);
  k_aggregate<<<N_V, 256, 0, stream>>>(xus, aw_u, xe_u2v, off_v, perm_v, xvt, h_v, N_V);

  // weights -> bf16 transposed; xe_e -> bf16
  k_wt<<<(896 * 256 + 255) / 256, 256, 0, stream>>>(W_v2u, Wt_v2u, 896, 256);
  k_wt<<<(896 * 256 + 255) / 256, 256, 0, stream>>>(W_u2v, Wt_u2v, 896, 256);
  k_wt<<<(576 * 64 + 255) / 256, 256, 0, stream>>>(W_e, Wt_e, 576, 64);
  k_cvt<<<20000, 256, 0, stream>>>(xe_e, xe_bf, N_E * 64 / 4);

  // GEMMs
  k_gemm<128><<<dim3(157, 2), 256, 0, stream>>>(h_u, 896, Wt_v2u, 896, out_u, 256, N_U, 896);
  k_gemm<128><<<dim3(157, 2), 256, 0, stream>>>(h_v, 896, Wt_u2v, 896, out_v, 256, N_V, 896);
  k_gemm<64><<<dim3(2500, 1), 256, 0, stream>>>(xe_bf, 64, Wt_e, 576, out_e, 64, N_E, 64);
  k_gemm<64><<<dim3(157, 1), 256, 0, stream>>>(h_u, 896, Wt_e + 64, 576, pu, 64, N_U, 256);
  k_gemm<64><<<dim3(157, 1), 256, 0, stream>>>(h_v, 896, Wt_e + 320, 576, pv, 64, N_V, 256);

  // edge assembly + stats, node col stats, BN
  k_edge_assemble<<<5000, 256, 0, stream>>>(out_e, pu, pv, row_e, col_e, sum_e, sq_e);
  k_colstats256<<<128, 256, 0, stream>>>(out_u, N_U, sum_u, sq_u);
  k_colstats256<<<128, 256, 0, stream>>>(out_v, N_V, sum_v, sq_v);
  k_bn<<<20000, 256, 0, stream>>>(out_u, (long)N_U * 256, 255, sum_u, sq_u, g_v2u, be_v2u, 1.f / N_U);
  k_bn<<<20000, 256, 0, stream>>>(out_v, (long)N_V * 256, 255, sum_v, sq_v, g_u2v, be_u2v, 1.f / N_V);
  k_bn<<<80000, 256, 0, stream>>>(out_e, (long)N_E * 64, 63, sum_e, sq_e, g_e, be_e, 1.f / N_E);
}

// Round 2
// 705.969 us; speedup vs baseline: 1.5727x; 1.5727x over previous
//
#include <hip/hip_runtime.h>
#include <stdint.h>

#define N_U 20000
#define N_V 20000
#define N_E 320000
#define EPS_F 1e-5f
#define NEG_HUGE -3.402823466e38f

using bf16x8 = __attribute__((__ext_vector_type__(8))) __bf16;
using f32x4  = __attribute__((__ext_vector_type__(4))) float;

__device__ __forceinline__ unsigned short f2bf(float f) {
  unsigned int u = __float_as_uint(f);
  u += 0x7FFFu + ((u >> 16) & 1u);
  return (unsigned short)(u >> 16);
}

__device__ __forceinline__ ushort4 bf4(float4 v) {
  return make_ushort4(f2bf(v.x), f2bf(v.y), f2bf(v.z), f2bf(v.w));
}

// ---- logits for both node sets: one wave per node ----
__global__ void k_logits2(const float* __restrict__ xus, const float* __restrict__ xvs,
                          const float* __restrict__ attn_u2v, const float* __restrict__ attn_v2u,
                          float* __restrict__ logits_u, float* __restrict__ logits_v) {
  int wid = (blockIdx.x * 256 + threadIdx.x) >> 6;
  int lane = threadIdx.x & 63;
  bool isU = wid < N_U;
  int node = isU ? wid : wid - N_U;
  const float4* x4 = reinterpret_cast<const float4*>(isU ? xus : xvs);
  const float4* a4 = reinterpret_cast<const float4*>(isU ? attn_u2v : attn_v2u);
  float4 xv = x4[(size_t)node * 64 + lane];
  float4 av = a4[lane];
  float s = xv.x * av.x + xv.y * av.y + xv.z * av.z + xv.w * av.w;
#pragma unroll
  for (int o = 32; o; o >>= 1) s += __shfl_down(s, o);
  if (lane == 0) (isU ? logits_u : logits_v)[node] = s;
}

// ---- global softmax stats (max, sumexp) — block 0: logits_u -> stat[0..1], block 1: logits_v -> stat[4..5]
__global__ void k_softmax_stat(const float* __restrict__ lu, const float* __restrict__ lv,
                               float* __restrict__ stat, int n) {
  const float* l = blockIdx.x ? lv : lu;
  float* st = stat + (blockIdx.x ? 4 : 0);
  __shared__ float red[16];
  __shared__ float sm;
  int t = threadIdx.x;
  float m = NEG_HUGE;
  for (int i = t; i < n; i += 1024) m = fmaxf(m, l[i]);
#pragma unroll
  for (int o = 32; o; o >>= 1) m = fmaxf(m, __shfl_down(m, o));
  if ((t & 63) == 0) red[t >> 6] = m;
  __syncthreads();
  if (t == 0) {
    float mm = red[0];
    for (int i = 1; i < 16; i++) mm = fmaxf(mm, red[i]);
    sm = mm;
  }
  __syncthreads();
  float mx = sm;
  float s = 0.f;
  for (int i = t; i < n; i += 1024) s += __expf(l[i] - mx);
#pragma unroll
  for (int o = 32; o; o >>= 1) s += __shfl_down(s, o);
  __syncthreads();
  if ((t & 63) == 0) red[t >> 6] = s;
  __syncthreads();
  if (t == 0) {
    float ss = 0.f;
    for (int i = 0; i < 16; i++) ss += red[i];
    st[0] = mx;
    st[1] = ss;
  }
}

// ---- CSR build, both graphs in one launch ----
__global__ void k_hist2(const int* __restrict__ d0, int* __restrict__ c0,
                        const int* __restrict__ d1, int* __restrict__ c1) {
  int b = blockIdx.x;
  if (b < 1250) atomicAdd(&c0[d0[b * 256 + threadIdx.x]], 1);
  else atomicAdd(&c1[d1[(b - 1250) * 256 + threadIdx.x]], 1);
}

__global__ void k_scan2(const int* __restrict__ cnt0, int* __restrict__ off0, int* __restrict__ cur0,
                        const int* __restrict__ cnt1, int* __restrict__ off1, int* __restrict__ cur1,
                        int n) {
  const int* cnt = blockIdx.x ? cnt1 : cnt0;
  int* off = blockIdx.x ? off1 : off0;
  int* cur = blockIdx.x ? cur1 : cur0;
  __shared__ int warpsum[16];
  __shared__ int carry;
  int t = threadIdx.x;
  if (t == 0) carry = 0;
  __syncthreads();
  for (int base = 0; base < n; base += 1024) {
    int i = base + t;
    int v = (i < n) ? cnt[i] : 0;
    int lane = t & 63, w = t >> 6;
    int incl = v;
#pragma unroll
    for (int o = 1; o < 64; o <<= 1) {
      int u = __shfl_up(incl, o);
      if (lane >= o) incl += u;
    }
    if (lane == 63) warpsum[w] = incl;
    __syncthreads();
    if (t == 0) {
      int s = 0;
      for (int k = 0; k < 16; k++) { int x = warpsum[k]; warpsum[k] = s; s += x; }
    }
    __syncthreads();
    int excl = incl - v + warpsum[w] + carry;
    if (i < n) { off[i] = excl; cur[i] = excl; }
    __syncthreads();
    if (t == 1023) carry = excl + v;
    __syncthreads();
  }
  if (t == 0) off[n] = carry;
}

__global__ void k_scatter2(const int* __restrict__ d0, const int* __restrict__ s0,
                           int* __restrict__ cur0, int2* __restrict__ p0,
                           const int* __restrict__ d1, const int* __restrict__ s1,
                           int* __restrict__ cur1, int2* __restrict__ p1) {
  int b = blockIdx.x;
  if (b < 1250) {
    int e = b * 256 + threadIdx.x;
    int p = atomicAdd(&cur0[d0[e]], 1);
    p0[p] = make_int2(e, s0[e]);
  } else {
    int e = (b - 1250) * 256 + threadIdx.x;
    int p = atomicAdd(&cur1[d1[e]], 1);
    p1[p] = make_int2(e, s1[e]);
  }
}

// ---- aggregation: one WAVE per destination node, both graphs in one launch ----
__global__ __launch_bounds__(256) void k_agg(
    const float* __restrict__ xvs, const float* __restrict__ xus,
    const float* __restrict__ logits_v, const float* __restrict__ logits_u,
    const float* __restrict__ smstat,
    const float* __restrict__ xe_v2u, const float* __restrict__ xe_u2v,
    const int* __restrict__ off_u, const int* __restrict__ off_v,
    const int2* __restrict__ perm_u, const int2* __restrict__ perm_v,
    const float* __restrict__ xut, const float* __restrict__ xvt,
    unsigned short* __restrict__ h_u, unsigned short* __restrict__ h_v) {
  int wid = (blockIdx.x * 256 + threadIdx.x) >> 6;
  int lane = threadIdx.x & 63;
  bool isU = wid < N_U;
  int node = isU ? wid : wid - N_U;
  const float4* xsrc4 = reinterpret_cast<const float4*>(isU ? xvs : xus);
  const float* lg = isU ? logits_v : logits_u;
  float mx = smstat[isU ? 4 : 0];
  float inv_se = 1.f / smstat[isU ? 5 : 1];
  const float* xe = isU ? xe_v2u : xe_u2v;
  const int* off = isU ? off_u : off_v;
  const int2* perm = isU ? perm_u : perm_v;
  const float4* xt4 = reinterpret_cast<const float4*>(isU ? xut : xvt);
  unsigned short* h = isU ? h_u : h_v;

  int beg = off[node], end = off[node + 1];
  float4 s = {0.f, 0.f, 0.f, 0.f};
  float4 m4 = {NEG_HUGE, NEG_HUGE, NEG_HUGE, NEG_HUGE};
  float se = 0.f, me = NEG_HUGE;

  for (int c = beg; c < end; c += 64) {
    int n = end - c;
    n = n > 64 ? 64 : n;
    int2 pe = perm[c + (lane < n ? lane : 0)];
    float av = __expf(lg[pe.y] - mx) * inv_se;
    int j = 0;
    for (; j + 4 <= n; j += 4) {
      int ey0 = __shfl(pe.y, j + 0), ex0 = __shfl(pe.x, j + 0); float a0 = __shfl(av, j + 0);
      int ey1 = __shfl(pe.y, j + 1), ex1 = __shfl(pe.x, j + 1); float a1 = __shfl(av, j + 1);
      int ey2 = __shfl(pe.y, j + 2), ex2 = __shfl(pe.x, j + 2); float a2 = __shfl(av, j + 2);
      int ey3 = __shfl(pe.y, j + 3), ex3 = __shfl(pe.x, j + 3); float a3 = __shfl(av, j + 3);
      float4 v0 = xsrc4[(size_t)ey0 * 64 + lane];
      float4 v1 = xsrc4[(size_t)ey1 * 64 + lane];
      float4 v2 = xsrc4[(size_t)ey2 * 64 + lane];
      float4 v3 = xsrc4[(size_t)ey3 * 64 + lane];
      float e0 = xe[(size_t)ex0 * 64 + lane];
      float e1 = xe[(size_t)ex1 * 64 + lane];
      float e2 = xe[(size_t)ex2 * 64 + lane];
      float e3 = xe[(size_t)ex3 * 64 + lane];
      float4 w0 = {a0 * v0.x, a0 * v0.y, a0 * v0.z, a0 * v0.w};
      float4 w1 = {a1 * v1.x, a1 * v1.y, a1 * v1.z, a1 * v1.w};
      float4 w2 = {a2 * v2.x, a2 * v2.y, a2 * v2.z, a2 * v2.w};
      float4 w3 = {a3 * v3.x, a3 * v3.y, a3 * v3.z, a3 * v3.w};
      s.x += w0.x + w1.x + w2.x + w3.x;
      s.y += w0.y + w1.y + w2.y + w3.y;
      s.z += w0.z + w1.z + w2.z + w3.z;
      s.w += w0.w + w1.w + w2.w + w3.w;
      m4.x = fmaxf(fmaxf(fmaxf(m4.x, w0.x), fmaxf(w1.x, w2.x)), w3.x);
      m4.y = fmaxf(fmaxf(fmaxf(m4.y, w0.y), fmaxf(w1.y, w2.y)), w3.y);
      m4.z = fmaxf(fmaxf(fmaxf(m4.z, w0.z), fmaxf(w1.z, w2.z)), w3.z);
      m4.w = fmaxf(fmaxf(fmaxf(m4.w, w0.w), fmaxf(w1.w, w2.w)), w3.w);
      se += e0 + e1 + e2 + e3;
      me = fmaxf(fmaxf(fmaxf(me, e0), fmaxf(e1, e2)), e3);
    }
    for (; j < n; j++) {
      int ey = __shfl(pe.y, j), ex = __shfl(pe.x, j);
      float a = __shfl(av, j);
      float4 v = xsrc4[(size_t)ey * 64 + lane];
      float ev = xe[(size_t)ex * 64 + lane];
      s.x += a * v.x; s.y += a * v.y; s.z += a * v.z; s.w += a * v.w;
      m4.x = fmaxf(m4.x, a * v.x); m4.y = fmaxf(m4.y, a * v.y);
      m4.z = fmaxf(m4.z, a * v.z); m4.w = fmaxf(m4.w, a * v.w);
      se += ev; me = fmaxf(me, ev);
    }
  }

  int deg = end - beg;
  float inv = 1.f / (float)(deg > 0 ? deg : 1);
  size_t hb = (size_t)node * 896;
  ushort4* h4 = reinterpret_cast<ushort4*>(h + hb);
  float4 self = xt4[(size_t)node * 64 + lane];
  h4[lane] = bf4(self);
  h4[64 + lane] = bf4(make_float4(s.x * inv, s.y * inv, s.z * inv, s.w * inv));
  float4 mo = deg > 0 ? m4 : make_float4(0.f, 0.f, 0.f, 0.f);
  h4[128 + lane] = bf4(mo);
  h[hb + 768 + lane] = f2bf(se * inv);
  h[hb + 832 + lane] = f2bf(deg > 0 ? me : 0.f);
}

// ---- all weight transposes (fp32 [K][N] -> bf16 [N][K]) in one launch ----
__global__ void k_wt_all(const float* __restrict__ W0, const float* __restrict__ W1,
                         const float* __restrict__ W2, unsigned short* __restrict__ T0,
                         unsigned short* __restrict__ T1, unsigned short* __restrict__ T2) {
  int i = blockIdx.x * 256 + threadIdx.x;
  const float* W;
  unsigned short* T;
  int K, N;
  if (i < 229376) { W = W0; T = T0; K = 896; N = 256; }
  else if (i < 458752) { i -= 229376; W = W1; T = T1; K = 896; N = 256; }
  else { i -= 458752; if (i >= 36864) return; W = W2; T = T2; K = 576; N = 64; }
  int k = i / N, n = i % N;
  T[(size_t)n * K + k] = f2bf(W[i]);
}

// ---- bf16 MFMA GEMM, z selects among 2 problem instances; optional fused col-stats ----
template <int TN, bool STATS>
__global__ __launch_bounds__(256) void k_gemm(
    const unsigned short* __restrict__ A0, const unsigned short* __restrict__ A1, int lda,
    const unsigned short* __restrict__ B0, const unsigned short* __restrict__ B1, int ldb,
    float* __restrict__ C0, float* __restrict__ C1, int ldc, int M, int K,
    float* __restrict__ sum0, float* __restrict__ sum1,
    float* __restrict__ sq0, float* __restrict__ sq1) {
  constexpr int WAVES_N = TN / 64;
  constexpr int WAVES_M = 4 / WAVES_N;
  constexpr int WTM = 128 / WAVES_M;
  constexpr int MT = WTM / 16;
  constexpr int NT = 4;
  constexpr int LS = 56;  // padded k-stride (ushorts): 112B rows, 16B-aligned, ~2-way banks

  __shared__ __align__(16) unsigned short As[128 * LS];
  __shared__ __align__(16) unsigned short Bs[TN * LS];
  __shared__ float ssum[TN], ssq[TN];

  const unsigned short* A = blockIdx.z ? A1 : A0;
  const unsigned short* B = blockIdx.z ? B1 : B0;
  float* C = blockIdx.z ? C1 : C0;
  float* sum = blockIdx.z ? sum1 : sum0;
  float* sq = blockIdx.z ? sq1 : sq0;

  const int t = threadIdx.x;
  const int m0 = blockIdx.x * 128;
  const int n0 = blockIdx.y * TN;
  const int lane = t & 63;
  const int w = t >> 6;
  const int wm = w % WAVES_M;
  const int wn = w / WAVES_M;

  if (STATS && t < TN) { ssum[t] = 0.f; ssq[t] = 0.f; }

  f32x4 acc[MT][NT];
#pragma unroll
  for (int i = 0; i < MT; i++)
#pragma unroll
    for (int j = 0; j < NT; j++) acc[i][j] = (f32x4){0.f, 0.f, 0.f, 0.f};

  const int arow_l = wm * WTM + (lane & 15);
  const int koff_l = (lane >> 4) * 8;

  for (int k0 = 0; k0 < K; k0 += 32) {
    if (k0) __syncthreads();
#pragma unroll
    for (int p = 0; p < 2; p++) {
      int c = t + p * 256;
      int row = c >> 2, kc = c & 3;
      int rg = m0 + row;
      rg = rg < M ? rg : M - 1;
      *reinterpret_cast<uint4*>(&As[row * LS + kc * 8]) =
          *reinterpret_cast<const uint4*>(A + (size_t)rg * lda + k0 + kc * 8);
    }
#pragma unroll
    for (int p = 0; p < TN / 64; p++) {
      int c = t + p * 256;
      int row = c >> 2, kc = c & 3;
      *reinterpret_cast<uint4*>(&Bs[row * LS + kc * 8]) =
          *reinterpret_cast<const uint4*>(B + (size_t)(n0 + row) * ldb + k0 + kc * 8);
    }
    __syncthreads();
    bf16x8 af[MT], bfv[NT];
#pragma unroll
    for (int i = 0; i < MT; i++)
      af[i] = *reinterpret_cast<const bf16x8*>(&As[(arow_l + i * 16) * LS + koff_l]);
#pragma unroll
    for (int j = 0; j < NT; j++)
      bfv[j] = *reinterpret_cast<const bf16x8*>(&Bs[(wn * 64 + j * 16 + (lane & 15)) * LS + koff_l]);
#pragma unroll
    for (int i = 0; i < MT; i++)
#pragma unroll
      for (int j = 0; j < NT; j++)
        acc[i][j] = __builtin_amdgcn_mfma_f32_16x16x32_bf16(af[i], bfv[j], acc[i][j], 0, 0, 0);
  }

  float st[NT], qt[NT];
#pragma unroll
  for (int j = 0; j < NT; j++) { st[j] = 0.f; qt[j] = 0.f; }
#pragma unroll
  for (int i = 0; i < MT; i++) {
#pragma unroll
    for (int j = 0; j < NT; j++) {
      int col = n0 + wn * 64 + j * 16 + (lane & 15);
#pragma unroll
      for (int r = 0; r < 4; r++) {
        int row = m0 + wm * WTM + i * 16 + (lane >> 4) * 4 + r;
        if (row < M) {
          float v = acc[i][j][r];
          C[(size_t)row * ldc + col] = v;
          if (STATS) { st[j] += v; qt[j] += v * v; }
        }
      }
    }
  }
  if (STATS) {
#pragma unroll
    for (int j = 0; j < NT; j++) {
      st[j] += __shfl_xor(st[j], 16); st[j] += __shfl_xor(st[j], 32);
      qt[j] += __shfl_xor(qt[j], 16); qt[j] += __shfl_xor(qt[j], 32);
    }
    if (lane < 16) {
#pragma unroll
      for (int j = 0; j < NT; j++) {
        atomicAdd(&ssum[wn * 64 + j * 16 + lane], st[j]);
        atomicAdd(&ssq[wn * 64 + j * 16 + lane], qt[j]);
      }
    }
    __syncthreads();
    if (t < TN) {
      atomicAdd(&sum[n0 + t], ssum[t]);
      atomicAdd(&sq[n0 + t], ssq[t]);
    }
  }
}

// ---- fused edge GEMM: pe = bf16(xe_e) @ W1, += pu[row_e] + pv[col_e], col-stats ----
__global__ __launch_bounds__(256) void k_gemm_e(
    const float* __restrict__ xe_e, const unsigned short* __restrict__ Wt,  // [64][576], k<64
    const int* __restrict__ rowe, const int* __restrict__ cole,
    const float* __restrict__ pu, const float* __restrict__ pv,
    float* __restrict__ OutE, float* __restrict__ sum, float* __restrict__ sq) {
  constexpr int LSB = 72;  // padded k-stride: 144B rows
  __shared__ __align__(16) unsigned short Bs[64 * LSB];
  __shared__ float ssum[64], ssq[64];
  int t = threadIdx.x;
  int lane = t & 63, w = t >> 6;
  if (t < 64) { ssum[t] = 0.f; ssq[t] = 0.f; }
  {
    int row = t >> 2, seg = t & 3;
    const uint4* src = reinterpret_cast<const uint4*>(Wt + (size_t)row * 576 + seg * 16);
    uint4* dst = reinterpret_cast<uint4*>(&Bs[row * LSB + seg * 16]);
    dst[0] = src[0];
    dst[1] = src[1];
  }
  __syncthreads();

  int m0 = blockIdx.x * 128;
  f32x4 acc[2][4];
#pragma unroll
  for (int i = 0; i < 2; i++)
#pragma unroll
    for (int j = 0; j < 4; j++) acc[i][j] = (f32x4){0.f, 0.f, 0.f, 0.f};

#pragma unroll
  for (int k0 = 0; k0 < 64; k0 += 32) {
    bf16x8 af[2], bfv[4];
#pragma unroll
    for (int i = 0; i < 2; i++) {
      int row = m0 + w * 32 + i * 16 + (lane & 15);
      const float4* ap = reinterpret_cast<const float4*>(xe_e + (size_t)row * 64 + k0 + (lane >> 4) * 8);
      float4 a0 = ap[0], a1 = ap[1];
      union { bf16x8 v; ushort4 u[2]; } pk;
      pk.u[0] = bf4(a0);
      pk.u[1] = bf4(a1);
      af[i] = pk.v;
    }
#pragma unroll
    for (int j = 0; j < 4; j++)
      bfv[j] = *reinterpret_cast<const bf16x8*>(&Bs[(j * 16 + (lane & 15)) * LSB + k0 + (lane >> 4) * 8]);
#pragma unroll
    for (int i = 0; i < 2; i++)
#pragma unroll
      for (int j = 0; j < 4; j++)
        acc[i][j] = __builtin_amdgcn_mfma_f32_16x16x32_bf16(af[i], bfv[j], acc[i][j], 0, 0, 0);
  }

  float st[4] = {0.f, 0.f, 0.f, 0.f}, qt[4] = {0.f, 0.f, 0.f, 0.f};
#pragma unroll
  for (int i = 0; i < 2; i++) {
    int base = m0 + w * 32 + i * 16 + (lane >> 4) * 4;
#pragma unroll
    for (int r = 0; r < 4; r++) {
      int e = base + r;
      int ru = rowe[e], cv = cole[e];
      const float* pur = pu + (size_t)ru * 64;
      const float* pvr = pv + (size_t)cv * 64;
#pragma unroll
      for (int j = 0; j < 4; j++) {
        int col = j * 16 + (lane & 15);
        float v = acc[i][j][r] + pur[col] + pvr[col];
        OutE[(size_t)e * 64 + col] = v;
        st[j] += v;
        qt[j] += v * v;
      }
    }
  }
#pragma unroll
  for (int j = 0; j < 4; j++) {
    st[j] += __shfl_xor(st[j], 16); st[j] += __shfl_xor(st[j], 32);
    qt[j] += __shfl_xor(qt[j], 16); qt[j] += __shfl_xor(qt[j], 32);
  }
  if (lane < 16) {
#pragma unroll
    for (int j = 0; j < 4; j++) {
      atomicAdd(&ssum[j * 16 + lane], st[j]);
      atomicAdd(&ssq[j * 16 + lane], qt[j]);
    }
  }
  __syncthreads();
  if (t < 64) {
    atomicAdd(&sum[t], ssum[t]);
    atomicAdd(&sq[t], ssq[t]);
  }
}

// ---- BN apply, all three outputs, float4 per thread ----
__global__ void k_bn4(float* __restrict__ out_u, float* __restrict__ out_v,
                      float* __restrict__ out_e, const float* __restrict__ stats,
                      const float* __restrict__ g_u, const float* __restrict__ be_u,
                      const float* __restrict__ g_v, const float* __restrict__ be_v,
                      const float* __restrict__ g_e, const float* __restrict__ be_e) {
  int b = blockIdx.x;
  float* X;
  const float *sum, *sq, *g, *be;
  int cmask;
  float invn;
  long base;
  if (b < 5000) {
    X = out_u; base = (long)b * 1024; sum = stats; sq = stats + 256;
    g = g_u; be = be_u; cmask = 255; invn = 1.f / N_U;
  } else if (b < 10000) {
    X = out_v; base = (long)(b - 5000) * 1024; sum = stats + 512; sq = stats + 768;
    g = g_v; be = be_v; cmask = 255; invn = 1.f / N_V;
  } else {
    X = out_e; base = (long)(b - 10000) * 1024; sum = stats + 1024; sq = stats + 1088;
    g = g_e; be = be_e; cmask = 63; invn = 1.f / N_E;
  }
  long i4 = base + (long)threadIdx.x * 4;
  int c0 = (int)(i4 & cmask);
  float4 v = *reinterpret_cast<float4*>(X + i4);
  float r[4] = {v.x, v.y, v.z, v.w};
#pragma unroll
  for (int k = 0; k < 4; k++) {
    int c = c0 + k;
    float mu = sum[c] * invn;
    float var = sq[c] * invn - mu * mu;
    r[k] = (r[k] - mu) * rsqrtf(var + EPS_F) * g[c] + be[c];
  }
  *reinterpret_cast<float4*>(X + i4) = make_float4(r[0], r[1], r[2], r[3]);
}

extern "C" void kernel_launch(void* const* d_in, const int* in_sizes, int n_in, void* d_out,
                              int out_size, void* d_ws, size_t ws_size, hipStream_t stream) {
  (void)in_sizes; (void)n_in; (void)out_size; (void)ws_size;
  const float* xus = (const float*)d_in[0];
  const float* xut = (const float*)d_in[1];
  const float* xvs = (const float*)d_in[2];
  const float* xvt = (const float*)d_in[3];
  const float* xe_e = (const float*)d_in[4];
  const float* xe_v2u = (const float*)d_in[5];
  const float* xe_u2v = (const float*)d_in[6];
  const int* row_v2u = (const int*)d_in[7];
  const int* col_v2u = (const int*)d_in[8];
  const int* row_u2v = (const int*)d_in[9];
  const int* col_u2v = (const int*)d_in[10];
  const int* row_e = (const int*)d_in[11];
  const int* col_e = (const int*)d_in[12];
  const float* W_v2u = (const float*)d_in[14];
  const float* g_v2u = (const float*)d_in[16];
  const float* be_v2u = (const float*)d_in[17];
  const float* W_u2v = (const float*)d_in[19];
  const float* g_u2v = (const float*)d_in[21];
  const float* be_u2v = (const float*)d_in[22];
  const float* W_e = (const float*)d_in[23];
  const float* g_e = (const float*)d_in[25];
  const float* be_e = (const float*)d_in[26];
  const float* attn_v2u = (const float*)d_in[13];
  const float* attn_u2v = (const float*)d_in[18];

  char* p = (char*)d_ws;
  auto alloc = [&](size_t bytes) {
    char* r = p;
    p += (bytes + 15) & ~(size_t)15;
    return r;
  };
  // zero zone (contiguous prefix)
  int* cnt_u = (int*)alloc(N_U * 4);
  int* cnt_v = (int*)alloc(N_V * 4);
  float* stats = (float*)alloc(1152 * 4);
  size_t zero_bytes = (size_t)(p - (char*)d_ws);
  // rest
  int* off_u = (int*)alloc((N_U + 1) * 4);
  int* cur_u = (int*)alloc(N_U * 4);
  int2* perm_u = (int2*)alloc((size_t)N_E * 8);
  int* off_v = (int*)alloc((N_V + 1) * 4);
  int* cur_v = (int*)alloc(N_V * 4);
  int2* perm_v = (int2*)alloc((size_t)N_E * 8);
  float* logits_u = (float*)alloc(N_U * 4);
  float* logits_v = (float*)alloc(N_V * 4);
  float* smstat = (float*)alloc(8 * 4);
  unsigned short* h_u = (unsigned short*)alloc((size_t)N_U * 896 * 2);
  unsigned short* h_v = (unsigned short*)alloc((size_t)N_V * 896 * 2);
  unsigned short* Wt_v2u = (unsigned short*)alloc((size_t)896 * 256 * 2);
  unsigned short* Wt_u2v = (unsigned short*)alloc((size_t)896 * 256 * 2);
  unsigned short* Wt_e = (unsigned short*)alloc((size_t)576 * 64 * 2);
  float* pu = (float*)alloc((size_t)N_U * 64 * 4);
  float* pv = (float*)alloc((size_t)N_V * 64 * 4);

  float* out_u = (float*)d_out;
  float* out_v = out_u + (size_t)N_U * 256;
  float* out_e = out_v + (size_t)N_V * 256;

  hipMemsetAsync(d_ws, 0, zero_bytes, stream);

  k_logits2<<<10000, 256, 0, stream>>>(xus, xvs, attn_u2v, attn_v2u, logits_u, logits_v);
  k_softmax_stat<<<2, 1024, 0, stream>>>(logits_u, logits_v, smstat, N_U);
  k_hist2<<<2500, 256, 0, stream>>>(row_v2u, cnt_u, col_u2v, cnt_v);
  k_scan2<<<2, 1024, 0, stream>>>(cnt_u, off_u, cur_u, cnt_v, off_v, cur_v, N_U);
  k_scatter2<<<2500, 256, 0, stream>>>(row_v2u, col_v2u, cur_u, perm_u, col_u2v, row_u2v, cur_v, perm_v);
  k_agg<<<10000, 256, 0, stream>>>(xvs, xus, logits_v, logits_u, smstat, xe_v2u, xe_u2v,
                                   off_u, off_v, perm_u, perm_v, xut, xvt, h_u, h_v);
  k_wt_all<<<1936, 256, 0, stream>>>(W_v2u, W_u2v, W_e, Wt_v2u, Wt_u2v, Wt_e);

  // node GEMMs with fused BN col-stats (z: 0=u, 1=v)
  k_gemm<128, true><<<dim3(157, 2, 2), 256, 0, stream>>>(
      h_u, h_v, 896, Wt_v2u, Wt_u2v, 896, out_u, out_v, 256, N_U, 896,
      stats, stats + 512, stats + 256, stats + 768);
  // pu/pv GEMMs (z: 0=pu from h_u cols0..255, 1=pv)
  k_gemm<64, false><<<dim3(157, 1, 2), 256, 0, stream>>>(
      h_u, h_v, 896, Wt_e + 64, Wt_e + 320, 576, pu, pv, 64, N_U, 256,
      nullptr, nullptr, nullptr, nullptr);
  // fused edge GEMM + assemble + stats
  k_gemm_e<<<2500, 256, 0, stream>>>(xe_e, Wt_e, row_e, col_e, pu, pv, out_e,
                                     stats + 1024, stats + 1088);
  k_bn4<<<30000, 256, 0, stream>>>(out_u, out_v, out_e, stats, g_v2u, be_v2u,
                                   g_u2v, be_u2v, g_e, be_e);
}